// Round 1
// baseline (9082.089 us; speedup 1.0000x reference)
//
#include <hip/hip_runtime.h>
#include <hip/hip_bf16.h>
#include <math.h>

#define T_STEPS 256
#define B_SZ 64
#define DIN 512
#define H_SZ 1024
#define CH_SZ 2048
#define G3 6144
#define DOUT 512
#define TB 16384

typedef __attribute__((ext_vector_type(4))) float f32x4;
typedef __attribute__((ext_vector_type(8))) short s16x8;
typedef __attribute__((ext_vector_type(4))) short s16x4;
typedef __attribute__((ext_vector_type(8))) __bf16 bf16x8;

__device__ __forceinline__ unsigned short f2bf(float f) {
  unsigned u = __builtin_bit_cast(unsigned, f);
  u += 0x7fffu + ((u >> 16) & 1u);   // RNE
  return (unsigned short)(u >> 16);
}
__device__ __forceinline__ float bf2f(unsigned short h) {
  unsigned u = ((unsigned)h) << 16;
  return __builtin_bit_cast(float, u);
}
__device__ __forceinline__ f32x4 mfma16(s16x8 a, s16x8 b, f32x4 c) {
  return __builtin_amdgcn_mfma_f32_16x16x32_bf16(
      __builtin_bit_cast(bf16x8, a), __builtin_bit_cast(bf16x8, b), c, 0, 0, 0);
}

// ---------------------------------------------------------------------------
// C[M,N] = act(A[M,K] @ B[N,K]^T + bias[N]); A fp32 or bf16 (row stride lda),
// B bf16 row-major [N,K]. Output fp32 (Cf) or bf16 (Cb), row stride ldc.
// Block tile 128x128, 4 waves (2x2), each wave 64x64 via 4x4 MFMA 16x16x32.
// LDS rows padded to 40 elems (20-word stride -> 2-way bank alias = free).
// ACT: 0 none, 1 elu, 2 softplus+0.1
// ---------------------------------------------------------------------------
template<bool AF32, int ACT, bool OBF>
__global__ __launch_bounds__(256, 2)
void gemm_bt(const void* __restrict__ Ap, long lda,
             const unsigned short* __restrict__ Bp,
             const float* __restrict__ bias,
             float* __restrict__ Cf, unsigned short* __restrict__ Cb, long ldc,
             int K)
{
  __shared__ unsigned short sA[128 * 40];
  __shared__ unsigned short sB[128 * 40];
  const int tid  = threadIdx.x;
  const int lane = tid & 63;
  const int wave = tid >> 6;
  const int wm = wave & 1, wn = wave >> 1;
  const int l16 = lane & 15, quad = lane >> 4;
  const long m0 = (long)blockIdx.x * 128;
  const long n0 = (long)blockIdx.y * 128;
  const int srow = tid >> 1;
  const int sseg = (tid & 1) << 4;

  f32x4 acc[4][4] = {};

  for (int k0 = 0; k0 < K; k0 += 32) {
    if constexpr (AF32) {
      const float* A = (const float*)Ap + (m0 + srow) * lda + (k0 + sseg);
      f32x4 v0 = *(const f32x4*)(A + 0);
      f32x4 v1 = *(const f32x4*)(A + 4);
      f32x4 v2 = *(const f32x4*)(A + 8);
      f32x4 v3 = *(const f32x4*)(A + 12);
      s16x8 p0, p1;
      p0[0] = (short)f2bf(v0.x); p0[1] = (short)f2bf(v0.y);
      p0[2] = (short)f2bf(v0.z); p0[3] = (short)f2bf(v0.w);
      p0[4] = (short)f2bf(v1.x); p0[5] = (short)f2bf(v1.y);
      p0[6] = (short)f2bf(v1.z); p0[7] = (short)f2bf(v1.w);
      p1[0] = (short)f2bf(v2.x); p1[1] = (short)f2bf(v2.y);
      p1[2] = (short)f2bf(v2.z); p1[3] = (short)f2bf(v2.w);
      p1[4] = (short)f2bf(v3.x); p1[5] = (short)f2bf(v3.y);
      p1[6] = (short)f2bf(v3.z); p1[7] = (short)f2bf(v3.w);
      *(s16x8*)&sA[srow * 40 + sseg]     = p0;
      *(s16x8*)&sA[srow * 40 + sseg + 8] = p1;
    } else {
      const unsigned short* A = (const unsigned short*)Ap + (m0 + srow) * lda + (k0 + sseg);
      *(s16x8*)&sA[srow * 40 + sseg]     = *(const s16x8*)(A);
      *(s16x8*)&sA[srow * 40 + sseg + 8] = *(const s16x8*)(A + 8);
    }
    {
      const unsigned short* Bq = Bp + (n0 + srow) * (long)K + (k0 + sseg);
      *(s16x8*)&sB[srow * 40 + sseg]     = *(const s16x8*)(Bq);
      *(s16x8*)&sB[srow * 40 + sseg + 8] = *(const s16x8*)(Bq + 8);
    }
    __syncthreads();
    s16x8 af[4], bfr[4];
#pragma unroll
    for (int i = 0; i < 4; ++i) {
      af[i]  = *(const s16x8*)&sA[(wm * 64 + i * 16 + l16) * 40 + quad * 8];
      bfr[i] = *(const s16x8*)&sB[(wn * 64 + i * 16 + l16) * 40 + quad * 8];
    }
#pragma unroll
    for (int mi = 0; mi < 4; ++mi)
#pragma unroll
      for (int ni = 0; ni < 4; ++ni)
        acc[mi][ni] = mfma16(af[mi], bfr[ni], acc[mi][ni]);
    __syncthreads();
  }

#pragma unroll
  for (int mi = 0; mi < 4; ++mi) {
#pragma unroll
    for (int ni = 0; ni < 4; ++ni) {
      const long n = n0 + wn * 64 + ni * 16 + l16;
      const float bv = bias[n];
#pragma unroll
      for (int i = 0; i < 4; ++i) {
        const long m = m0 + wm * 64 + mi * 16 + quad * 4 + i;
        float v = acc[mi][ni][i] + bv;
        if constexpr (ACT == 1) v = v > 0.f ? v : expm1f(v);
        if constexpr (ACT == 2) v = fmaxf(v, 0.f) + log1pf(expf(-fabsf(v))) + 0.1f;
        if constexpr (OBF) Cb[m * ldc + n] = f2bf(v);
        else               Cf[m * ldc + n] = v;
      }
    }
  }
}

// ---------------------------------------------------------------------------
// One GRU step: gh = h @ Whh^T (+bhh), fused gates.
// 128 blocks; block handles 16 h-units (jb..jb+15) for all 3 gates, M=64.
// 4 waves: wave w covers batch rows [16w,16w+16). BK=64, K=2048 -> 32 slabs.
// ---------------------------------------------------------------------------
__global__ __launch_bounds__(256, 2)
void gru_step(const unsigned short* __restrict__ hprev,  // [64,2048] bf16
              const unsigned short* __restrict__ Whhb,   // [6144,2048] bf16
              const unsigned short* __restrict__ gxt,    // [64,6144] bf16
              const float* __restrict__ bhh,             // [6144]
              const float* __restrict__ hold,            // [64,2048] fp32 or null
              float* __restrict__ hout,                  // [64,2048] fp32
              unsigned short* __restrict__ hnewb)        // [64,2048] bf16
{
  __shared__ unsigned short sH[64 * 72];  // padded stride 72 (36 words -> 2-way)
  __shared__ unsigned short sW[48 * 72];  // rows: gate*16 + j
  const int tid  = threadIdx.x;
  const int lane = tid & 63;
  const int wave = tid >> 6;
  const int l16 = lane & 15, quad = lane >> 4;
  const int jb = blockIdx.x * 16;

  f32x4 aR = {}, aZ = {}, aN = {};

  const int hrow = tid >> 2;
  const int hseg = (tid & 3) << 4;

  for (int k0 = 0; k0 < CH_SZ; k0 += 64) {
    {
      const unsigned short* src = hprev + (long)hrow * CH_SZ + k0 + hseg;
      *(s16x8*)&sH[hrow * 72 + hseg]     = *(const s16x8*)(src);
      *(s16x8*)&sH[hrow * 72 + hseg + 8] = *(const s16x8*)(src + 8);
    }
    if (tid < 192) {
      const int wr = tid >> 2;           // 0..47
      const int gate = wr >> 4, j = wr & 15;
      const unsigned short* src = Whhb + ((long)gate * CH_SZ + jb + j) * CH_SZ + k0 + hseg;
      *(s16x8*)&sW[wr * 72 + hseg]     = *(const s16x8*)(src);
      *(s16x8*)&sW[wr * 72 + hseg + 8] = *(const s16x8*)(src + 8);
    }
    __syncthreads();
#pragma unroll
    for (int kk = 0; kk < 2; ++kk) {
      s16x8 a  = *(const s16x8*)&sH[(wave * 16 + l16) * 72 + kk * 32 + quad * 8];
      s16x8 br = *(const s16x8*)&sW[( 0 + l16) * 72 + kk * 32 + quad * 8];
      s16x8 bz = *(const s16x8*)&sW[(16 + l16) * 72 + kk * 32 + quad * 8];
      s16x8 bn = *(const s16x8*)&sW[(32 + l16) * 72 + kk * 32 + quad * 8];
      aR = mfma16(a, br, aR);
      aZ = mfma16(a, bz, aZ);
      aN = mfma16(a, bn, aN);
    }
    __syncthreads();
  }

  const int j = jb + l16;
  const float br_ = bhh[j], bz_ = bhh[CH_SZ + j], bn_ = bhh[2 * CH_SZ + j];
#pragma unroll
  for (int i = 0; i < 4; ++i) {
    const int m = wave * 16 + quad * 4 + i;
    const long g = (long)m * G3;
    const float xr = bf2f(gxt[g + j]);
    const float xz = bf2f(gxt[g + CH_SZ + j]);
    const float xn = bf2f(gxt[g + 2 * CH_SZ + j]);
    const float r = 1.f / (1.f + expf(-(xr + aR[i] + br_)));
    const float z = 1.f / (1.f + expf(-(xz + aZ[i] + bz_)));
    const float n = tanhf(xn + r * (aN[i] + bn_));
    const float ho = hold ? hold[(long)m * CH_SZ + j] : 0.f;
    const float hv = (1.f - z) * n + z * ho;
    hout[(long)m * CH_SZ + j] = hv;
    hnewb[(long)m * CH_SZ + j] = f2bf(hv);
  }
}

__global__ void cast_f32_bf16(const float* __restrict__ s, unsigned short* __restrict__ d, long n) {
  long i = ((long)blockIdx.x * blockDim.x + threadIdx.x) * 4;
  if (i + 3 < n) {
    f32x4 v = *(const f32x4*)(s + i);
    s16x4 p;
    p[0] = (short)f2bf(v.x); p[1] = (short)f2bf(v.y);
    p[2] = (short)f2bf(v.z); p[3] = (short)f2bf(v.w);
    *(s16x4*)(d + i) = p;
  }
}

__global__ void zero_u32(unsigned int* p, int n) {
  int i = blockIdx.x * blockDim.x + threadIdx.x;
  if (i < n) p[i] = 0u;
}

extern "C" void kernel_launch(void* const* d_in, const int* in_sizes, int n_in,
                              void* d_out, int out_size, void* d_ws, size_t ws_size,
                              hipStream_t stream)
{
  const float* x    = (const float*)d_in[0];
  const float* We   = (const float*)d_in[1];
  const float* be   = (const float*)d_in[2];
  const float* Wih  = (const float*)d_in[3];
  const float* bih  = (const float*)d_in[4];
  const float* Whh  = (const float*)d_in[5];
  const float* bhh  = (const float*)d_in[6];
  const float* Wmu  = (const float*)d_in[7];
  const float* bmu  = (const float*)d_in[8];
  const float* Wsig = (const float*)d_in[9];
  const float* bsig = (const float*)d_in[10];

  float* out = (float*)d_out;
  float* mu  = out;
  float* sg  = out + (long)TB * DOUT;
  float* hid = out + 2L * TB * DOUT;

  // workspace layout (bf16 buffers), ~276 MB total
  char* w = (char*)d_ws;
  unsigned short* Web  = (unsigned short*)w; w += (long)H_SZ * DIN * 2;
  unsigned short* Wihb = (unsigned short*)w; w += (long)G3 * H_SZ * 2;
  unsigned short* Whhb = (unsigned short*)w; w += (long)G3 * CH_SZ * 2;
  unsigned short* Wmub = (unsigned short*)w; w += (long)DOUT * H_SZ * 2;
  unsigned short* Wsgb = (unsigned short*)w; w += (long)DOUT * H_SZ * 2;
  unsigned short* xeb  = (unsigned short*)w; w += (long)TB * H_SZ * 2;
  unsigned short* gxb  = (unsigned short*)w; w += (long)TB * G3 * 2;
  unsigned short* hbA  = (unsigned short*)w; w += (long)B_SZ * CH_SZ * 2;
  unsigned short* hbB  = (unsigned short*)w; w += (long)B_SZ * CH_SZ * 2;

  auto cast = [&](const float* s, unsigned short* d, long n) {
    int blocks = (int)((n / 4 + 255) / 256);
    cast_f32_bf16<<<blocks, 256, 0, stream>>>(s, d, n);
  };
  cast(We,   Web,  (long)H_SZ * DIN);
  cast(Wih,  Wihb, (long)G3 * H_SZ);
  cast(Whh,  Whhb, (long)G3 * CH_SZ);
  cast(Wmu,  Wmub, (long)DOUT * H_SZ);
  cast(Wsig, Wsgb, (long)DOUT * H_SZ);
  {
    int n = B_SZ * CH_SZ * 2 / 4;  // bytes/4
    zero_u32<<<(n + 255) / 256, 256, 0, stream>>>((unsigned int*)hbA, n);
  }

  // enc: xe = elu(x @ We^T + be) -> bf16 [TB, H]
  gemm_bt<true, 1, true><<<dim3(TB / 128, H_SZ / 128), 256, 0, stream>>>(
      x, (long)DIN, Web, be, nullptr, xeb, (long)H_SZ, DIN);

  // gx = xe @ Wih^T + bih -> bf16 [TB, 6144]
  gemm_bt<false, 0, true><<<dim3(TB / 128, G3 / 128), 256, 0, stream>>>(
      xeb, (long)H_SZ, Wihb, bih, nullptr, gxb, (long)G3, H_SZ);

  // recurrence: 256 sequential steps
  for (int t = 0; t < T_STEPS; ++t) {
    const unsigned short* hp = (t & 1) ? hbB : hbA;
    unsigned short*       hn = (t & 1) ? hbA : hbB;
    const float* ho = t ? (hid + (long)(t - 1) * B_SZ * CH_SZ) : nullptr;
    gru_step<<<dim3(CH_SZ / 16), 256, 0, stream>>>(
        hp, Whhb, gxb + (long)t * B_SZ * G3, bhh, ho,
        hid + (long)t * B_SZ * CH_SZ, hn);
  }

  // heads: mu = elu(h_mu @ Wmu^T + bmu); sig = softplus(h_sig @ Wsig^T + bsig) + 0.1
  gemm_bt<true, 1, false><<<dim3(TB / 128, DOUT / 128), 256, 0, stream>>>(
      hid, (long)CH_SZ, Wmub, bmu, mu, nullptr, (long)DOUT, H_SZ);
  gemm_bt<true, 2, false><<<dim3(TB / 128, DOUT / 128), 256, 0, stream>>>(
      hid + H_SZ, (long)CH_SZ, Wsgb, bsig, sg, nullptr, (long)DOUT, H_SZ);
}